// Round 8
// baseline (238.800 us; speedup 1.0000x reference)
//
#include <hip/hip_runtime.h>
#include <math.h>

#define INC 64
#define HID 16
#define NB 8

__device__ __forceinline__ void atomicMaxF(float* addr, float val) {
    // float-max-via-int trick: valid for mixed signs, target initialized to -inf
    if (val >= 0.0f) atomicMax((int*)addr, __float_as_int(val));
    else             atomicMin((unsigned int*)addr, __float_as_uint(val));
}

__device__ __forceinline__ float4 add4(float4 a, float4 b) {
    return make_float4(a.x + b.x, a.y + b.y, a.z + b.z, a.w + b.w);
}
__device__ __forceinline__ float4 max4(float4 a, float4 b) {
    return make_float4(fmaxf(a.x, b.x), fmaxf(a.y, b.y),
                       fmaxf(a.z, b.z), fmaxf(a.w, b.w));
}

// ---------------- init workspace (ws is poisoned 0xAA before every launch) ---
__global__ void k_init(float* seg_sum, float* seg_max, int* counts, float* sm_pad) {
    int t = threadIdx.x;
    if (t < NB * INC) { seg_sum[t] = 0.0f; seg_max[t] = -INFINITY; }
    else if (t < NB * INC + NB) counts[t - NB * INC] = 0;
    else if (t < NB * INC + NB + 2) sm_pad[t - NB * INC - NB] = 0.0f; // pad row N
}

// ------------- segmented sum/max/count over sorted batch_idx -----------------
// Block = 256 pts (4 waves x 64). Full+uniform block: each wave loads its 64
// points into 16 LIVE float4 regs guard-free (static indices -> registers,
// 16 loads in flight), tree-reduces, LDS-combines, ONE atomic set per block.
__global__ __launch_bounds__(256)
void k_reduce(const float* __restrict__ F, const int* __restrict__ bidx,
              float* __restrict__ seg_sum, float* __restrict__ seg_max,
              int* __restrict__ counts, int N) {
    __shared__ float4 lsum[4][16];
    __shared__ float4 lmax[4][16];

    int lane = threadIdx.x & 63;
    int wid  = threadIdx.x >> 6;
    int bs   = blockIdx.x * 256;
    if (bs >= N) return;
    int sub = lane >> 4;
    int ch  = (lane & 15) << 2;

    bool full = (bs + 256 <= N);
    int bblk = bidx[bs];
    bool uni = full && (bidx[bs + 255] == bblk);

    if (uni) {
        const float* fb = F + (size_t)(bs + wid * 64 + sub) * INC + ch;
        float4 f[16];
        #pragma unroll
        for (int i = 0; i < 16; ++i)
            f[i] = *reinterpret_cast<const float4*>(fb + (size_t)(4 * i) * INC);
        // tree reduce (shorter dep chains, loads stay in flight)
        float4 s, m;
        {
            float4 t0 = add4(f[0], f[1]),  t1 = add4(f[2], f[3]);
            float4 t2 = add4(f[4], f[5]),  t3 = add4(f[6], f[7]);
            float4 t4 = add4(f[8], f[9]),  t5 = add4(f[10], f[11]);
            float4 t6 = add4(f[12], f[13]), t7 = add4(f[14], f[15]);
            s = add4(add4(add4(t0, t1), add4(t2, t3)),
                     add4(add4(t4, t5), add4(t6, t7)));
        }
        {
            float4 t0 = max4(f[0], f[1]),  t1 = max4(f[2], f[3]);
            float4 t2 = max4(f[4], f[5]),  t3 = max4(f[6], f[7]);
            float4 t4 = max4(f[8], f[9]),  t5 = max4(f[10], f[11]);
            float4 t6 = max4(f[12], f[13]), t7 = max4(f[14], f[15]);
            m = max4(max4(max4(t0, t1), max4(t2, t3)),
                     max4(max4(t4, t5), max4(t6, t7)));
        }
        // combine the 4 sub-copies (lanes differing in bits 4,5)
        #pragma unroll
        for (int msk = 16; msk < 64; msk <<= 1) {
            s.x += __shfl_xor(s.x, msk); s.y += __shfl_xor(s.y, msk);
            s.z += __shfl_xor(s.z, msk); s.w += __shfl_xor(s.w, msk);
            m.x = fmaxf(m.x, __shfl_xor(m.x, msk));
            m.y = fmaxf(m.y, __shfl_xor(m.y, msk));
            m.z = fmaxf(m.z, __shfl_xor(m.z, msk));
            m.w = fmaxf(m.w, __shfl_xor(m.w, msk));
        }
        if (lane < 16) { lsum[wid][lane] = s; lmax[wid][lane] = m; }
        __syncthreads();
        if (wid == 0 && lane < 16) {
            float4 S = lsum[0][lane], M = lmax[0][lane];
            #pragma unroll
            for (int w = 1; w < 4; ++w) {
                S = add4(S, lsum[w][lane]);
                M = max4(M, lmax[w][lane]);
            }
            float* ss = seg_sum + bblk * INC + (lane << 2);
            atomicAdd(ss + 0, S.x); atomicAdd(ss + 1, S.y);
            atomicAdd(ss + 2, S.z); atomicAdd(ss + 3, S.w);
            float* sx = seg_max + bblk * INC + (lane << 2);
            atomicMaxF(sx + 0, M.x); atomicMaxF(sx + 1, M.y);
            atomicMaxF(sx + 2, M.z); atomicMaxF(sx + 3, M.w);
            if (lane == 0) atomicAdd(&counts[bblk], 256);
        }
        return;
    }

    // ---- partial or non-uniform block (<=8 total): per-point tracking ----
    int start = bs + wid * 64;
    if (start >= N) return;
    int pend = min(start + 64, N);
    bool isCnt = (lane & 15) == 0;
    float4 sum = make_float4(0.f, 0.f, 0.f, 0.f);
    float4 mx  = make_float4(-INFINITY, -INFINITY, -INFINITY, -INFINITY);
    int cnt = 0, cur = -1;
    for (int p = start; p < pend; p += 4) {
        int pp = p + sub;
        int b = (pp < N) ? bidx[pp] : -2;
        if (b != cur) {
            if (cur >= 0) {
                float* ss = seg_sum + cur * INC + ch;
                atomicAdd(ss + 0, sum.x); atomicAdd(ss + 1, sum.y);
                atomicAdd(ss + 2, sum.z); atomicAdd(ss + 3, sum.w);
                float* sx = seg_max + cur * INC + ch;
                atomicMaxF(sx + 0, mx.x); atomicMaxF(sx + 1, mx.y);
                atomicMaxF(sx + 2, mx.z); atomicMaxF(sx + 3, mx.w);
                if (isCnt && cnt) atomicAdd(&counts[cur], cnt);
            }
            sum = make_float4(0.f, 0.f, 0.f, 0.f);
            mx  = make_float4(-INFINITY, -INFINITY, -INFINITY, -INFINITY);
            cnt = 0; cur = b;
        }
        if (b >= 0) {
            const float4 v = *reinterpret_cast<const float4*>(F + (size_t)pp * INC + ch);
            sum = add4(sum, v); mx = max4(mx, v);
            cnt += (int)isCnt;
        }
    }
    if (cur >= 0) {
        float* ss = seg_sum + cur * INC + ch;
        atomicAdd(ss + 0, sum.x); atomicAdd(ss + 1, sum.y);
        atomicAdd(ss + 2, sum.z); atomicAdd(ss + 3, sum.w);
        float* sx = seg_max + cur * INC + ch;
        atomicMaxF(sx + 0, mx.x); atomicMaxF(sx + 1, mx.y);
        atomicMaxF(sx + 2, mx.z); atomicMaxF(sx + 3, mx.w);
        if (isCnt && cnt) atomicAdd(&counts[cur], cnt);
    }
}

// -------- tiny per-batch MLP: gate[b][c] = sigmoid(mlp(avg)+mlp(mx)) ---------
__global__ void k_gate(const float* __restrict__ seg_sum, const float* __restrict__ seg_max,
                       const int* __restrict__ counts,
                       const float* __restrict__ W1, const float* __restrict__ b1,
                       const float* __restrict__ W2, const float* __restrict__ b2,
                       float* __restrict__ gate) {
    __shared__ float s_avg[NB * INC], s_mx[NB * INC];
    __shared__ float s_W1[INC * HID], s_W2[HID * INC];
    __shared__ float s_ha[NB * HID], s_hm[NB * HID];
    int t = threadIdx.x; // 512 threads
    s_W1[t] = W1[t]; s_W1[t + 512] = W1[t + 512];
    s_W2[t] = W2[t]; s_W2[t + 512] = W2[t + 512];
    {
        int b = t >> 6;
        float c = (float)counts[b];
        s_avg[t] = seg_sum[t] / c;
        s_mx[t]  = seg_max[t];
    }
    __syncthreads();
    if (t < NB * HID) {
        int b = t >> 4, jj = t & (HID - 1);
        float ha = b1[jj], hm = b1[jj];
        #pragma unroll
        for (int c = 0; c < INC; ++c) {
            float w = s_W1[c * HID + jj];
            ha += s_avg[b * INC + c] * w;
            hm += s_mx[b * INC + c] * w;
        }
        s_ha[t] = fmaxf(ha, 0.f);
        s_hm[t] = fmaxf(hm, 0.f);
    }
    __syncthreads();
    {
        int b = t >> 6, c = t & 63;
        float o = 2.f * b2[c];
        #pragma unroll
        for (int jj = 0; jj < HID; ++jj)
            o += (s_ha[b * HID + jj] + s_hm[b * HID + jj]) * s_W2[jj * INC + c];
        gate[t] = 1.f / (1.f + expf(-o));
    }
}

// ------- per-point channel mean/max of z = F*gate -> sm[N][2] ---------------
// Block = 128 pts (4 waves x 32). Full+uniform: 8 guard-free live-reg loads.
__global__ __launch_bounds__(256)
void k_sm(const float* __restrict__ F, const int* __restrict__ bidx,
          const float* __restrict__ gate, float* __restrict__ sm, int N) {
    int lane = threadIdx.x & 63;
    int wid  = threadIdx.x >> 6;
    int bs   = blockIdx.x * 128;
    if (bs >= N) return;
    int sub = lane >> 4;
    int ch  = (lane & 15) << 2;
    bool wr = (lane & 15) == 0;
    float2* sm2 = reinterpret_cast<float2*>(sm);

    bool full = (bs + 128 <= N);
    int b0 = bidx[bs];
    bool uni = full && (bidx[bs + 127] == b0);

    if (uni) {
        const float4 g = *reinterpret_cast<const float4*>(gate + b0 * INC + ch);
        int start = bs + wid * 32;
        const float* fb = F + (size_t)(start + sub) * INC + ch;
        float4 f[8];
        #pragma unroll
        for (int i = 0; i < 8; ++i)
            f[i] = *reinterpret_cast<const float4*>(fb + (size_t)(4 * i) * INC);
        float s[8], m[8];
        #pragma unroll
        for (int i = 0; i < 8; ++i) {
            float4 z = make_float4(f[i].x * g.x, f[i].y * g.y,
                                   f[i].z * g.z, f[i].w * g.w);
            s[i] = z.x + z.y + z.z + z.w;
            m[i] = fmaxf(fmaxf(z.x, z.y), fmaxf(z.z, z.w));
        }
        #pragma unroll
        for (int msk = 1; msk < 16; msk <<= 1) {
            #pragma unroll
            for (int i = 0; i < 8; ++i) {
                s[i] += __shfl_xor(s[i], msk);
                m[i] = fmaxf(m[i], __shfl_xor(m[i], msk));
            }
        }
        if (wr) {
            #pragma unroll
            for (int i = 0; i < 8; ++i)
                sm2[start + 4 * i + sub] = make_float2(s[i] * (1.f / 64.f), m[i]);
        }
        return;
    }

    // partial / non-uniform (<=8 blocks): per-point
    int start = bs + wid * 32;
    if (start >= N) return;
    int pend = min(start + 32, N);
    for (int p = start; p < pend; p += 4) {
        int pp = p + sub;
        float s = 0.f, m = -INFINITY;
        if (pp < N) {
            int b = bidx[pp];
            float4 v = *reinterpret_cast<const float4*>(F + (size_t)pp * INC + ch);
            float4 g = *reinterpret_cast<const float4*>(gate + b * INC + ch);
            float4 z = make_float4(v.x * g.x, v.y * g.y, v.z * g.z, v.w * g.w);
            s = z.x + z.y + z.z + z.w;
            m = fmaxf(fmaxf(z.x, z.y), fmaxf(z.z, z.w));
        }
        #pragma unroll
        for (int msk = 1; msk < 16; msk <<= 1) {
            s += __shfl_xor(s, msk);
            m = fmaxf(m, __shfl_xor(m, msk));
        }
        if (wr && pp < N)
            sm2[pp] = make_float2(s * (1.f / 64.f), m);
    }
}

// ------- gather 27 neighbors' sm, 2ch conv, final out = z * sigmoid(c) ------
// Block = 128 pts. Full+uniform: preload ALL 16 nbr indices for the wave's 8
// groups, then all 8 F loads, then all 16 sm gathers -> one latency round-trip
// per chunk instead of one per group.
__global__ __launch_bounds__(256, 2)
void k_out(const float* __restrict__ F, const int* __restrict__ bidx,
           const int* __restrict__ nbr, const float* __restrict__ gate,
           const float* __restrict__ sm, const float* __restrict__ cw,
           float* __restrict__ out, int N) {
    int lane = threadIdx.x & 63;
    int wid  = threadIdx.x >> 6;
    int bs   = blockIdx.x * 128;
    if (bs >= N) return;
    int sub = lane >> 4;
    int ch  = (lane & 15) << 2;
    int j   = lane & 15;
    const float2* sm2 = reinterpret_cast<const float2*>(sm);
    float2 cwa = make_float2(cw[2 * j], cw[2 * j + 1]);
    float2 cwb = (j < 11) ? make_float2(cw[2 * (16 + j)], cw[2 * (16 + j) + 1])
                          : make_float2(0.f, 0.f);

    bool full = (bs + 128 <= N);
    int b0 = bidx[bs];
    bool uni = full && (bidx[bs + 127] == b0);

    if (uni) {
        int start = bs + wid * 32;
        // 1) all neighbor indices for the chunk (16 independent 4B loads)
        int i1[8], i2[8];
        #pragma unroll
        for (int gi = 0; gi < 8; ++gi) {
            int pp = start + 4 * gi + sub;
            i1[gi] = nbr[pp * 27 + j];
            i2[gi] = (j < 11) ? nbr[pp * 27 + 16 + j] : N;
        }
        // 2) all F loads (independent of indices)
        const float* fb = F + (size_t)(start + sub) * INC + ch;
        float4 v[8];
        #pragma unroll
        for (int gi = 0; gi < 8; ++gi)
            v[gi] = *reinterpret_cast<const float4*>(fb + (size_t)(4 * gi) * INC);
        // 3) all sm gathers (wait once for the idx loads, then 16 in flight)
        float2 A[8], B[8];
        #pragma unroll
        for (int gi = 0; gi < 8; ++gi) { A[gi] = sm2[i1[gi]]; B[gi] = sm2[i2[gi]]; }
        // 4) compute + write
        const float4 g4 = *reinterpret_cast<const float4*>(gate + b0 * INC + ch);
        #pragma unroll
        for (int gi = 0; gi < 8; ++gi) {
            float cpart = A[gi].x * cwa.x + A[gi].y * cwa.y
                        + B[gi].x * cwb.x + B[gi].y * cwb.y;
            #pragma unroll
            for (int msk = 1; msk < 16; msk <<= 1) cpart += __shfl_xor(cpart, msk);
            float sig = 1.f / (1.f + expf(-cpart));
            int pp = start + 4 * gi + sub;
            float4 o = make_float4(v[gi].x * g4.x * sig, v[gi].y * g4.y * sig,
                                   v[gi].z * g4.z * sig, v[gi].w * g4.w * sig);
            *reinterpret_cast<float4*>(out + (size_t)pp * INC + ch) = o;
        }
        return;
    }

    // partial / non-uniform (<=8 blocks): per-point
    int start = bs + wid * 32;
    if (start >= N) return;
    int pend = min(start + 32, N);
    for (int p = start; p < pend; p += 4) {
        int pp = p + sub;
        float cpart = 0.f;
        if (pp < N) {
            int rb = pp * 27;
            int q1 = nbr[rb + j];
            int q2 = (j < 11) ? nbr[rb + 16 + j] : N;
            float2 a = sm2[q1];
            float2 b = sm2[q2];
            cpart = a.x * cwa.x + a.y * cwa.y + b.x * cwb.x + b.y * cwb.y;
        }
        #pragma unroll
        for (int msk = 1; msk < 16; msk <<= 1) cpart += __shfl_xor(cpart, msk);
        if (pp < N) {
            float sig = 1.f / (1.f + expf(-cpart));
            int bb = bidx[pp];
            float4 fv = *reinterpret_cast<const float4*>(F + (size_t)pp * INC + ch);
            float4 g = *reinterpret_cast<const float4*>(gate + bb * INC + ch);
            float4 o = make_float4(fv.x * g.x * sig, fv.y * g.y * sig,
                                   fv.z * g.z * sig, fv.w * g.w * sig);
            *reinterpret_cast<float4*>(out + (size_t)pp * INC + ch) = o;
        }
    }
}

extern "C" void kernel_launch(void* const* d_in, const int* in_sizes, int n_in,
                              void* d_out, int out_size, void* d_ws, size_t ws_size,
                              hipStream_t stream) {
    const float* F    = (const float*)d_in[0];
    const int*   bidx = (const int*)d_in[1];
    const int*   nbr  = (const int*)d_in[2];
    const float* W1   = (const float*)d_in[3];
    const float* b1   = (const float*)d_in[4];
    const float* W2   = (const float*)d_in[5];
    const float* b2   = (const float*)d_in[6];
    const float* cw   = (const float*)d_in[7];
    float* out = (float*)d_out;
    int N = in_sizes[1];

    float* ws      = (float*)d_ws;
    float* seg_sum = ws;                        // 512
    float* seg_max = ws + NB * INC;             // 512
    int*   counts  = (int*)(ws + 2 * NB * INC); // 8 (+pad to 16)
    float* gate    = ws + 2 * NB * INC + 16;    // 512, 16B-aligned
    float* sm      = ws + 3 * NB * INC + 32;    // (N+1)*2, 8B-aligned

    k_init<<<1, 1024, 0, stream>>>(seg_sum, seg_max, counts, sm + (size_t)N * 2);

    int blocksR = (N + 255) / 256;      // 1172
    k_reduce<<<blocksR, 256, 0, stream>>>(F, bidx, seg_sum, seg_max, counts, N);

    k_gate<<<1, 512, 0, stream>>>(seg_sum, seg_max, counts, W1, b1, W2, b2, gate);

    int blocksS = (N + 127) / 128;      // 2344
    k_sm<<<blocksS, 256, 0, stream>>>(F, bidx, gate, sm, N);
    k_out<<<blocksS, 256, 0, stream>>>(F, bidx, nbr, gate, sm, cw, out, N);
}